// Round 5
// baseline (224.328 us; speedup 1.0000x reference)
//
#include <hip/hip_runtime.h>
#include <hip/hip_bf16.h>
#include <stdint.h>

typedef __hip_bfloat16 bf16;
typedef __attribute__((ext_vector_type(8))) short short8;   // 8 bf16 = 4 VGPRs (MFMA A/B frag)
typedef __attribute__((ext_vector_type(4))) float floatx4;  // MFMA C/D frag

#define AS1(p) ((const __attribute__((address_space(1))) void*)(p))
#define AS3(p) ((__attribute__((address_space(3))) void*)(p))

#define M_DIM 4096
#define H_DIM 1024
#define MEG   (1u << 20)    // 1M elements
#define LDS_BUF 24576       // one pipeline stage: A 8KB + B 16KB (3 stages = 72 KB)

// fp32 -> bf16 bits, round-to-nearest-even (inputs are finite)
__device__ __forceinline__ unsigned short f2bf(float f) {
    uint32_t u = __float_as_uint(f);
    uint32_t r = (u + 0x7FFFu + ((u >> 16) & 1u)) >> 16;
    return (unsigned short)r;
}

__device__ __forceinline__ float fast_sigmoid(float v) {
    return 1.0f / (1.0f + __expf(-v));
}
__device__ __forceinline__ float fast_tanh(float v) {
    return 2.0f / (1.0f + __expf(-2.0f * v)) - 1.0f;
}

// ---------------------------------------------------------------------------
// Kernel 1: convert fp32 inputs -> bf16 in workspace.
// ws layout (bf16 elems): x [0,4M) | h [4M,8M) | Wx{f,i,o,c} [8M+g*1M) |
//                         Wh{f,i,o,c} [12M+g*1M).  16M elems = 32 MB.
__global__ __launch_bounds__(256)
void convert_to_bf16(const float* __restrict__ x, const float* __restrict__ h,
                     const float* Wxf, const float* Wxi, const float* Wxo, const float* Wxc,
                     const float* Whf, const float* Whi, const float* Who, const float* Whc,
                     unsigned short* __restrict__ ws)
{
    const uint32_t idx0 = blockIdx.x * 2048u + threadIdx.x * 8u;
    const uint32_t t = blockIdx.x >> 9;   // 512 blocks per 1M elements (block-uniform)
    const float* src;
    uint32_t off;
    if (t < 4u)      { src = x; off = idx0; }
    else if (t < 8u) { src = h; off = idx0 - (4u << 20); }
    else {
        const uint32_t g = t - 8u;
        src = (g == 0) ? Wxf : (g == 1) ? Wxi : (g == 2) ? Wxo : (g == 3) ? Wxc
            : (g == 4) ? Whf : (g == 5) ? Whi : (g == 6) ? Who : Whc;
        off = idx0 & (MEG - 1u);
    }
    const float4 v0 = *(const float4*)(src + off);
    const float4 v1 = *(const float4*)(src + off + 4);
    short8 pk;
    pk[0] = (short)f2bf(v0.x); pk[1] = (short)f2bf(v0.y);
    pk[2] = (short)f2bf(v0.z); pk[3] = (short)f2bf(v0.w);
    pk[4] = (short)f2bf(v1.x); pk[5] = (short)f2bf(v1.y);
    pk[6] = (short)f2bf(v1.z); pk[7] = (short)f2bf(v1.w);
    *(short8*)(ws + idx0) = pk;
}

// ---------------------------------------------------------------------------
// Kernel 2: fused 4-gate GEMM + LSTM pointwise, 3-stage pipeline.
// Block: 256 threads (4 waves). Tile: 128 batch-rows x 64 hidden-cols x 4 gates.
// K loop: 64 steps of BK=32; phase 0 = x @ Wx^T, phase 1 = h @ Wh^T (accumulated).
// ONE s_barrier + one s_waitcnt vmcnt(6) per iteration (AITER shape): 12 staging
// loads/wave permanently in flight across 3 LDS stages.
//   iter kt: vmcnt(6) [loads(kt) retired]; s_barrier [all waves' loads(kt) landed,
//            and all waves' ds_reads of buf[(kt-1)%3] retired];
//            issue loads(kt+2) -> buf[(kt+2)%3] (== buf[(kt-1)%3], now safe);
//            compute(kt) from buf[kt%3].
// LDS k-group XOR swizzle (slot = kgrp ^ ((row>>1)&3)) on the DMA source side:
// ds_read_b128 bank conflicts measured 0.
// XCD swizzle: bid&7 = XCD (round-robin dispatch); each XCD sees only 2 of 16
// hidden-col tiles -> 2 MB weight working set fits the per-XCD 4 MB L2.
__global__ __launch_bounds__(256, 2)
void lstm_fused_kernel(const unsigned short* __restrict__ ws,
                       const float* __restrict__ c,
                       const float* __restrict__ bxf, const float* __restrict__ bhf,
                       const float* __restrict__ bxi, const float* __restrict__ bhi,
                       const float* __restrict__ bxo, const float* __restrict__ bho,
                       const float* __restrict__ bxc, const float* __restrict__ bhc,
                       float* __restrict__ out)
{
    __shared__ __align__(16) char lds[3 * LDS_BUF];

    const int tid  = threadIdx.x;
    const int w    = tid >> 6;
    const int lane = tid & 63;

    // XCD-aware block swizzle (1D grid of 512)
    const int bid = blockIdx.x;
    const int mx  = bid >> 4;                              // [0,32)
    const int ny  = ((bid & 7) << 1) | ((bid >> 3) & 1);   // [0,16)
    const int bm0 = mx * 128;
    const int bn0 = ny * 64;

    // staging: 24 chunks of 1 KB (16 rows x 32 k x 2B); wave w issues ch = w*6+i.
    // ch<8: A rows [ch*16,+16); ch>=8: b=ch-8, gate g=b>>2, n-subtile (b&3)*16.
    // Swizzled k-group: LDS slot (lane&3) holds global k-group (lane&3)^((lane>>3)&3).
    const uint32_t cg = (((uint32_t)lane & 3u) ^ (((uint32_t)lane >> 3) & 3u)) * 8u;
    const unsigned short* srcP0[6];
    const unsigned short* srcP1[6];
    uint32_t goff[6];   // per-lane element offset within source
    uint32_t loff[6];   // wave-uniform LDS byte base (within a stage)
#pragma unroll
    for (int i = 0; i < 6; ++i) {
        const int ch = w * 6 + i;
        if (ch < 8) {
            const int row = bm0 + ch * 16 + (lane >> 2);
            srcP0[i] = ws;                 // x
            srcP1[i] = ws + (4u << 20);    // h
            goff[i] = (uint32_t)row * 1024u + cg;
            loff[i] = (uint32_t)ch * 1024u;
        } else {
            const int b = ch - 8;
            const int g = b >> 2;
            const int n = bn0 + (b & 3) * 16 + (lane >> 2);
            srcP0[i] = ws + (8u << 20)  + (uint32_t)g * MEG;   // Wx_g
            srcP1[i] = ws + (12u << 20) + (uint32_t)g * MEG;   // Wh_g
            goff[i] = (uint32_t)n * 1024u + cg;
            loff[i] = 8192u + (uint32_t)b * 1024u;
        }
    }

    const int wrow  = (w & 1) * 64;    // 4 m-tiles
    const int wcol  = (w >> 1) * 32;   // 2 n-tiles
    const int lrc   = lane & 15;       // frag row (A) / col (B)
    const int lquad = lane >> 4;       // frag k-group (x8 elements)

    // reader-side swizzle: k-group lquad of row r lives at slot lquad^((r>>1)&3)
    const uint32_t kslot = (((uint32_t)lquad ^ (((uint32_t)lrc >> 1) & 3u))) * 8u;

    uint32_t aoff[4];
#pragma unroll
    for (int mt = 0; mt < 4; ++mt)
        aoff[mt] = (uint32_t)((wrow + mt * 16 + lrc) * 32) + kslot;
    uint32_t boff[4][2];
#pragma unroll
    for (int g = 0; g < 4; ++g)
#pragma unroll
        for (int nt = 0; nt < 2; ++nt)
            boff[g][nt] = (uint32_t)(g * 2048 + (wcol + nt * 16 + lrc) * 32) + kslot;

    floatx4 acc[4][4][2];
#pragma unroll
    for (int g = 0; g < 4; ++g)
#pragma unroll
        for (int mt = 0; mt < 4; ++mt)
#pragma unroll
            for (int nt = 0; nt < 2; ++nt)
                acc[g][mt][nt] = (floatx4){0.f, 0.f, 0.f, 0.f};

    auto issue_loads = [&](int kt, uint32_t stage) {
        const int phase = kt >> 5;
        const uint32_t k0 = (uint32_t)(kt & 31) * 32u;
        const uint32_t bb = stage * LDS_BUF;
#pragma unroll
        for (int i = 0; i < 6; ++i) {
            const unsigned short* src = phase ? srcP1[i] : srcP0[i];
            __builtin_amdgcn_global_load_lds(AS1(src + goff[i] + k0),
                                             AS3(lds + bb + loff[i]), 16, 0, 0);
        }
    };
    auto compute = [&](uint32_t stage) {
        const char* base = lds + stage * LDS_BUF;
        const bf16* lA = (const bf16*)base;
        const bf16* lB = (const bf16*)(base + 8192);
        short8 afr[4];
#pragma unroll
        for (int mt = 0; mt < 4; ++mt)
            afr[mt] = *(const short8*)(lA + aoff[mt]);
#pragma unroll
        for (int g = 0; g < 4; ++g) {
#pragma unroll
            for (int nt = 0; nt < 2; ++nt) {
                const short8 bfr = *(const short8*)(lB + boff[g][nt]);
#pragma unroll
                for (int mt = 0; mt < 4; ++mt)
                    acc[g][mt][nt] = __builtin_amdgcn_mfma_f32_16x16x32_bf16(
                        afr[mt], bfr, acc[g][mt][nt], 0, 0, 0);
            }
        }
    };

    // prologue: stages 0,1 in flight (12 outstanding/wave)
    issue_loads(0, 0);
    issue_loads(1, 1);

    uint32_t s_comp = 0;   // kt % 3
    uint32_t s_load = 2;   // (kt+2) % 3
    for (int kt = 0; kt < 62; ++kt) {
        // wait own loads(kt) retired (12 outstanding -> keep 6: loads(kt+1))
        asm volatile("s_waitcnt vmcnt(6)\ns_barrier" ::: "memory");
        issue_loads(kt + 2, s_load);
        compute(s_comp);
        s_comp = (s_comp == 2) ? 0 : s_comp + 1;
        s_load = (s_load == 2) ? 0 : s_load + 1;
    }
    asm volatile("s_waitcnt vmcnt(6)\ns_barrier" ::: "memory");   // loads(62) done
    compute(s_comp);
    s_comp = (s_comp == 2) ? 0 : s_comp + 1;
    asm volatile("s_waitcnt vmcnt(0)\ns_barrier" ::: "memory");   // loads(63) done
    compute(s_comp);

    // epilogue.  C/D layout: col = lane&15, row = (lane>>4)*4 + reg
    float* out_ct = out;
    float* out_ht = out + (size_t)M_DIM * H_DIM;
#pragma unroll
    for (int nt = 0; nt < 2; ++nt) {
        const int col = bn0 + wcol + nt * 16 + lrc;
        const float bf_ = bxf[col] + bhf[col];
        const float bi_ = bxi[col] + bhi[col];
        const float bo_ = bxo[col] + bho[col];
        const float bc_ = bxc[col] + bhc[col];
#pragma unroll
        for (int mt = 0; mt < 4; ++mt) {
#pragma unroll
            for (int r = 0; r < 4; ++r) {
                const int row = bm0 + wrow + mt * 16 + lquad * 4 + r;
                const float gf = acc[0][mt][nt][r] + bf_;
                const float gi = acc[1][mt][nt][r] + bi_;
                const float go = acc[2][mt][nt][r] + bo_;
                const float gc = acc[3][mt][nt][r] + bc_;
                const float f    = fast_sigmoid(gf);
                const float ii   = fast_sigmoid(gi);
                const float o    = fast_sigmoid(go);
                const float ctil = fast_tanh(gc);
                const float cv   = c[(size_t)row * H_DIM + col];
                const float ctn  = f * cv + ctil * ii;
                const float htn  = fast_tanh(ctn) * o;
                out_ct[(size_t)row * H_DIM + col] = ctn;
                out_ht[(size_t)row * H_DIM + col] = htn;
            }
        }
    }
}

extern "C" void kernel_launch(void* const* d_in, const int* in_sizes, int n_in,
                              void* d_out, int out_size, void* d_ws, size_t ws_size,
                              hipStream_t stream) {
    (void)in_sizes; (void)n_in; (void)out_size; (void)ws_size;
    const float* x   = (const float*)d_in[0];
    const float* c   = (const float*)d_in[1];
    const float* h   = (const float*)d_in[2];
    const float* Wxf = (const float*)d_in[3];  const float* bxf = (const float*)d_in[4];
    const float* Whf = (const float*)d_in[5];  const float* bhf = (const float*)d_in[6];
    const float* Wxi = (const float*)d_in[7];  const float* bxi = (const float*)d_in[8];
    const float* Whi = (const float*)d_in[9];  const float* bhi = (const float*)d_in[10];
    const float* Wxo = (const float*)d_in[11]; const float* bxo = (const float*)d_in[12];
    const float* Who = (const float*)d_in[13]; const float* bho = (const float*)d_in[14];
    const float* Wxc = (const float*)d_in[15]; const float* bxc = (const float*)d_in[16];
    const float* Whc = (const float*)d_in[17]; const float* bhc = (const float*)d_in[18];
    float* out = (float*)d_out;
    unsigned short* ws = (unsigned short*)d_ws;   // 16M bf16 elements = 32 MB

    convert_to_bf16<<<8192, 256, 0, stream>>>(x, h,
        Wxf, Wxi, Wxo, Wxc, Whf, Whi, Who, Whc, ws);

    lstm_fused_kernel<<<512, 256, 0, stream>>>(ws, c,
        bxf, bhf, bxi, bhi, bxo, bho, bxc, bhc, out);
}

// Round 6
// 217.016 us; speedup vs baseline: 1.0337x; 1.0337x over previous
//
#include <hip/hip_runtime.h>
#include <hip/hip_bf16.h>
#include <stdint.h>

typedef __hip_bfloat16 bf16;
typedef __attribute__((ext_vector_type(8))) short short8;   // 8 bf16 = 4 VGPRs (MFMA A/B frag)
typedef __attribute__((ext_vector_type(4))) float floatx4;  // MFMA C/D frag

#define AS1(p) ((const __attribute__((address_space(1))) void*)(p))
#define AS3(p) ((__attribute__((address_space(3))) void*)(p))

#define M_DIM 4096
#define H_DIM 1024
#define MEG   (1u << 20)    // 1M elements
#define LDS_BUF 24576       // one pipeline stage: A 8KB + B 16KB (3 stages = 72 KB)

// fp32 -> bf16 bits, round-to-nearest-even (inputs are finite)
__device__ __forceinline__ unsigned short f2bf(float f) {
    uint32_t u = __float_as_uint(f);
    uint32_t r = (u + 0x7FFFu + ((u >> 16) & 1u)) >> 16;
    return (unsigned short)r;
}

__device__ __forceinline__ float fast_sigmoid(float v) {
    return 1.0f / (1.0f + __expf(-v));
}
__device__ __forceinline__ float fast_tanh(float v) {
    return 2.0f / (1.0f + __expf(-2.0f * v)) - 1.0f;
}

// ---------------------------------------------------------------------------
// Kernel 1: convert fp32 inputs -> bf16 in workspace.
// ws layout (bf16 elems): x [0,4M) | h [4M,8M) | Wx{f,i,o,c} [8M+g*1M) |
//                         Wh{f,i,o,c} [12M+g*1M).  16M elems = 32 MB.
__global__ __launch_bounds__(256)
void convert_to_bf16(const float* __restrict__ x, const float* __restrict__ h,
                     const float* Wxf, const float* Wxi, const float* Wxo, const float* Wxc,
                     const float* Whf, const float* Whi, const float* Who, const float* Whc,
                     unsigned short* __restrict__ ws)
{
    const uint32_t idx0 = blockIdx.x * 2048u + threadIdx.x * 8u;
    const uint32_t t = blockIdx.x >> 9;   // 512 blocks per 1M elements (block-uniform)
    const float* src;
    uint32_t off;
    if (t < 4u)      { src = x; off = idx0; }
    else if (t < 8u) { src = h; off = idx0 - (4u << 20); }
    else {
        const uint32_t g = t - 8u;
        src = (g == 0) ? Wxf : (g == 1) ? Wxi : (g == 2) ? Wxo : (g == 3) ? Wxc
            : (g == 4) ? Whf : (g == 5) ? Whi : (g == 6) ? Who : Whc;
        off = idx0 & (MEG - 1u);
    }
    const float4 v0 = *(const float4*)(src + off);
    const float4 v1 = *(const float4*)(src + off + 4);
    short8 pk;
    pk[0] = (short)f2bf(v0.x); pk[1] = (short)f2bf(v0.y);
    pk[2] = (short)f2bf(v0.z); pk[3] = (short)f2bf(v0.w);
    pk[4] = (short)f2bf(v1.x); pk[5] = (short)f2bf(v1.y);
    pk[6] = (short)f2bf(v1.z); pk[7] = (short)f2bf(v1.w);
    *(short8*)(ws + idx0) = pk;
}

// ---------------------------------------------------------------------------
// Kernel 2: fused 4-gate GEMM + LSTM pointwise, 3-stage pipeline, 512 threads.
// Block: 512 threads (8 waves). Tile: 128 batch-rows x 64 hidden-cols x 4 gates.
// 2 blocks/CU (72 KB LDS) -> 16 waves/CU = 4 waves/SIMD for latency hiding.
// K loop: 64 steps of BK=32; phase 0 = x @ Wx^T, phase 1 = h @ Wh^T (accumulated).
// ONE s_barrier + one s_waitcnt vmcnt(3) per iteration: 3 staging chunks/wave/iter,
// 6 permanently in flight across 3 LDS stages.
//   iter kt: vmcnt(3) [own loads(kt) retired]; s_barrier [all waves' loads(kt)
//            landed, all ds_reads of buf[(kt-1)%3] retired];
//            issue loads(kt+2) -> buf[(kt+2)%3]; compute(kt) from buf[kt%3].
// Wave w: rows (w&1)*64..+64 (4 m-tiles), col group (w>>1)*16 in each of the
// 4 gates (4 B-frags) -> 16 MFMAs, acc[4][4] = 64 regs, gate-local epilogue.
// LDS k-group XOR swizzle (slot = kgrp ^ ((row>>1)&3)): 0 bank conflicts.
__global__ __launch_bounds__(512, 4)
void lstm_fused_kernel(const unsigned short* __restrict__ ws,
                       const float* __restrict__ c,
                       const float* __restrict__ bxf, const float* __restrict__ bhf,
                       const float* __restrict__ bxi, const float* __restrict__ bhi,
                       const float* __restrict__ bxo, const float* __restrict__ bho,
                       const float* __restrict__ bxc, const float* __restrict__ bhc,
                       float* __restrict__ out)
{
    __shared__ __align__(16) char lds[3 * LDS_BUF];

    const int tid  = threadIdx.x;
    const int w    = tid >> 6;     // 0..7
    const int lane = tid & 63;

    // XCD-aware block swizzle (1D grid of 512)
    const int bid = blockIdx.x;
    const int mx  = bid >> 4;                              // [0,32)
    const int ny  = ((bid & 7) << 1) | ((bid >> 3) & 1);   // [0,16)
    const int bm0 = mx * 128;
    const int bn0 = ny * 64;

    // staging: 24 chunks of 1 KB (16 rows x 32 k x 2B); wave w issues ch = w*3+i.
    // ch<8: A rows [ch*16,+16); ch>=8: b=ch-8, gate g=b>>2, n-subtile (b&3)*16.
    // Writer swizzle: LDS k-slot (lane&3) holds global k-group (lane&3)^((lane>>3)&3).
    const uint32_t cg = (((uint32_t)lane & 3u) ^ (((uint32_t)lane >> 3) & 3u)) * 8u;
    const unsigned short* srcP0[3];
    const unsigned short* srcP1[3];
    uint32_t goff[3];   // per-lane element offset within source
    uint32_t loff[3];   // wave-uniform LDS byte base (within a stage)
#pragma unroll
    for (int i = 0; i < 3; ++i) {
        const int ch = w * 3 + i;
        if (ch < 8) {
            const int row = bm0 + ch * 16 + (lane >> 2);
            srcP0[i] = ws;                 // x
            srcP1[i] = ws + (4u << 20);    // h
            goff[i] = (uint32_t)row * 1024u + cg;
            loff[i] = (uint32_t)ch * 1024u;
        } else {
            const int b = ch - 8;
            const int g = b >> 2;
            const int n = bn0 + (b & 3) * 16 + (lane >> 2);
            srcP0[i] = ws + (8u << 20)  + (uint32_t)g * MEG;   // Wx_g
            srcP1[i] = ws + (12u << 20) + (uint32_t)g * MEG;   // Wh_g
            goff[i] = (uint32_t)n * 1024u + cg;
            loff[i] = 8192u + (uint32_t)b * 1024u;
        }
    }

    const int wrow  = (w & 1) * 64;    // 4 m-tiles
    const int wcol  = (w >> 1) * 16;   // one 16-col group within each gate
    const int lrc   = lane & 15;       // frag row (A) / col (B)
    const int lquad = lane >> 4;       // frag k-group (x8 elements)

    // reader-side swizzle: k-group lquad of row r lives at slot lquad^((r>>1)&3);
    // tile offsets are multiples of 16 so (r>>1)&3 == (lrc>>1)&3.
    const uint32_t kslot = (((uint32_t)lquad ^ (((uint32_t)lrc >> 1) & 3u))) * 8u;

    uint32_t aoff[4];
#pragma unroll
    for (int mt = 0; mt < 4; ++mt)
        aoff[mt] = (uint32_t)((wrow + mt * 16 + lrc) * 32) + kslot;
    uint32_t boff[4];
#pragma unroll
    for (int g = 0; g < 4; ++g)
        boff[g] = (uint32_t)(g * 2048 + (wcol + lrc) * 32) + kslot;

    floatx4 acc[4][4];   // [gate][m-tile] = 64 fp32/lane
#pragma unroll
    for (int g = 0; g < 4; ++g)
#pragma unroll
        for (int mt = 0; mt < 4; ++mt)
            acc[g][mt] = (floatx4){0.f, 0.f, 0.f, 0.f};

    auto issue_loads = [&](int kt, uint32_t stage) {
        const int phase = kt >> 5;
        const uint32_t k0 = (uint32_t)(kt & 31) * 32u;
        const uint32_t bb = stage * LDS_BUF;
#pragma unroll
        for (int i = 0; i < 3; ++i) {
            const unsigned short* src = phase ? srcP1[i] : srcP0[i];
            __builtin_amdgcn_global_load_lds(AS1(src + goff[i] + k0),
                                             AS3(lds + bb + loff[i]), 16, 0, 0);
        }
    };
    auto compute = [&](uint32_t stage) {
        const char* base = lds + stage * LDS_BUF;
        const bf16* lA = (const bf16*)base;
        const bf16* lB = (const bf16*)(base + 8192);
        short8 afr[4];
#pragma unroll
        for (int mt = 0; mt < 4; ++mt)
            afr[mt] = *(const short8*)(lA + aoff[mt]);
#pragma unroll
        for (int g = 0; g < 4; ++g) {
            const short8 bfr = *(const short8*)(lB + boff[g]);
#pragma unroll
            for (int mt = 0; mt < 4; ++mt)
                acc[g][mt] = __builtin_amdgcn_mfma_f32_16x16x32_bf16(
                    afr[mt], bfr, acc[g][mt], 0, 0, 0);
        }
    };

    // prologue: stages 0,1 in flight (6 outstanding/wave)
    issue_loads(0, 0);
    issue_loads(1, 1);

    uint32_t s_comp = 0;   // kt % 3
    uint32_t s_load = 2;   // (kt+2) % 3
    for (int kt = 0; kt < 62; ++kt) {
        // own loads(kt) retired; loads(kt+1) (3) stay in flight
        asm volatile("s_waitcnt vmcnt(3)\ns_barrier" ::: "memory");
        issue_loads(kt + 2, s_load);
        compute(s_comp);
        s_comp = (s_comp == 2) ? 0 : s_comp + 1;
        s_load = (s_load == 2) ? 0 : s_load + 1;
    }
    asm volatile("s_waitcnt vmcnt(3)\ns_barrier" ::: "memory");   // loads(62) done
    compute(s_comp);
    s_comp = (s_comp == 2) ? 0 : s_comp + 1;
    asm volatile("s_waitcnt vmcnt(0)\ns_barrier" ::: "memory");   // loads(63) done
    compute(s_comp);

    // epilogue.  C/D layout: col = lane&15, row = (lane>>4)*4 + reg
    float* out_ct = out;
    float* out_ht = out + (size_t)M_DIM * H_DIM;
    {
        const int col = bn0 + wcol + lrc;
        const float bf_ = bxf[col] + bhf[col];
        const float bi_ = bxi[col] + bhi[col];
        const float bo_ = bxo[col] + bho[col];
        const float bc_ = bxc[col] + bhc[col];
#pragma unroll
        for (int mt = 0; mt < 4; ++mt) {
#pragma unroll
            for (int r = 0; r < 4; ++r) {
                const int row = bm0 + wrow + mt * 16 + lquad * 4 + r;
                const float gf = acc[0][mt][r] + bf_;
                const float gi = acc[1][mt][r] + bi_;
                const float go = acc[2][mt][r] + bo_;
                const float gc = acc[3][mt][r] + bc_;
                const float f    = fast_sigmoid(gf);
                const float ii   = fast_sigmoid(gi);
                const float o    = fast_sigmoid(go);
                const float ctil = fast_tanh(gc);
                const float cv   = c[(size_t)row * H_DIM + col];
                const float ctn  = f * cv + ctil * ii;
                const float htn  = fast_tanh(ctn) * o;
                out_ct[(size_t)row * H_DIM + col] = ctn;
                out_ht[(size_t)row * H_DIM + col] = htn;
            }
        }
    }
}

extern "C" void kernel_launch(void* const* d_in, const int* in_sizes, int n_in,
                              void* d_out, int out_size, void* d_ws, size_t ws_size,
                              hipStream_t stream) {
    (void)in_sizes; (void)n_in; (void)out_size; (void)ws_size;
    const float* x   = (const float*)d_in[0];
    const float* c   = (const float*)d_in[1];
    const float* h   = (const float*)d_in[2];
    const float* Wxf = (const float*)d_in[3];  const float* bxf = (const float*)d_in[4];
    const float* Whf = (const float*)d_in[5];  const float* bhf = (const float*)d_in[6];
    const float* Wxi = (const float*)d_in[7];  const float* bxi = (const float*)d_in[8];
    const float* Whi = (const float*)d_in[9];  const float* bhi = (const float*)d_in[10];
    const float* Wxo = (const float*)d_in[11]; const float* bxo = (const float*)d_in[12];
    const float* Who = (const float*)d_in[13]; const float* bho = (const float*)d_in[14];
    const float* Wxc = (const float*)d_in[15]; const float* bxc = (const float*)d_in[16];
    const float* Whc = (const float*)d_in[17]; const float* bhc = (const float*)d_in[18];
    float* out = (float*)d_out;
    unsigned short* ws = (unsigned short*)d_ws;   // 16M bf16 elements = 32 MB

    convert_to_bf16<<<8192, 256, 0, stream>>>(x, h,
        Wxf, Wxi, Wxo, Wxc, Whf, Whi, Who, Whc, ws);

    lstm_fused_kernel<<<512, 512, 0, stream>>>(ws, c,
        bxf, bhf, bxi, bhi, bxo, bho, bxc, bhc, out);
}

// Round 7
// 207.125 us; speedup vs baseline: 1.0831x; 1.0478x over previous
//
#include <hip/hip_runtime.h>
#include <hip/hip_bf16.h>
#include <stdint.h>

typedef __hip_bfloat16 bf16;
typedef __attribute__((ext_vector_type(8))) short short8;   // 8 bf16 = 4 VGPRs (MFMA A/B frag)
typedef __attribute__((ext_vector_type(4))) float floatx4;  // MFMA C/D frag

#define AS1(p) ((const __attribute__((address_space(1))) void*)(p))
#define AS3(p) ((__attribute__((address_space(3))) void*)(p))

#define M_DIM 4096
#define H_DIM 1024
#define MEG   (1u << 20)    // 1M elements
#define LDS_BUF 24576       // one pipeline stage: A 8KB + B 16KB (3 stages = 72 KB)

// fp32 -> bf16 bits, round-to-nearest-even (inputs are finite)
__device__ __forceinline__ unsigned short f2bf(float f) {
    uint32_t u = __float_as_uint(f);
    uint32_t r = (u + 0x7FFFu + ((u >> 16) & 1u)) >> 16;
    return (unsigned short)r;
}

__device__ __forceinline__ float fast_sigmoid(float v) {
    return 1.0f / (1.0f + __expf(-v));
}
__device__ __forceinline__ float fast_tanh(float v) {
    return 2.0f / (1.0f + __expf(-2.0f * v)) - 1.0f;
}

// ---------------------------------------------------------------------------
// Kernel 1: PACK fp32 -> bf16 chunks in the exact swizzled LDS-image order the
// GEMM stages them.  One chunk = 1 KB = [16 rows][4 k-slots][8 bf16], where
// slot = kgroup ^ ((row>>1)&3) (the bank-conflict swizzle, pre-baked here).
// ws chunk map (chunk id W, 512 bf16 each, 32768 chunks = 32 MB):
//   W in [0,8192):      x  chunks, W = (mx*32+kt)*8+ch          (mx<32,kt<32,ch<8)
//   W in [8192,16384):  h  chunks, same decode
//   W in [16384,24576): Wx chunks, W-16384 = ((ny*16+g*4+b4)*32)+kt
//   W in [24576,32768): Wh chunks, same decode
// GEMM then DMAs each chunk as base + lane*16 over CONTIGUOUS memory:
// 8 full 128-B lines per global_load_lds instead of 16 half-used lines.
__global__ __launch_bounds__(256)
void pack_bf16(const float* __restrict__ x, const float* __restrict__ h,
               const float* Wxf, const float* Wxi, const float* Wxo, const float* Wxc,
               const float* Whf, const float* Whi, const float* Who, const float* Whc,
               unsigned short* __restrict__ ws)
{
    const int w = threadIdx.x >> 6;
    const int l = threadIdx.x & 63;
    const uint32_t W = blockIdx.x * 4u + (uint32_t)w;   // chunk id [0, 32768)

    const uint32_t r  = (uint32_t)l >> 2;                       // row in chunk [0,16)
    const uint32_t kg = ((uint32_t)l & 3u) ^ ((r >> 1) & 3u);   // global k-group of this slot

    const float* src;
    uint32_t row, kt;
    if (W < 16384u) {                    // A-chunks (x / h)
        const uint32_t Wa = W & 8191u;
        const uint32_t ch = Wa & 7u;
        kt = (Wa >> 3) & 31u;
        const uint32_t mx = Wa >> 8;
        src = (W < 8192u) ? x : h;
        row = mx * 128u + ch * 16u + r;
    } else {                             // B-chunks (Wx_g / Wh_g)
        const uint32_t V = W & 8191u;
        kt = V & 31u;
        uint32_t U = V >> 5;
        const uint32_t b4 = U & 3u;
        const uint32_t g  = (U >> 2) & 3u;
        const uint32_t ny = U >> 4;
        if (W < 24576u)
            src = (g == 0) ? Wxf : (g == 1) ? Wxi : (g == 2) ? Wxo : Wxc;
        else
            src = (g == 0) ? Whf : (g == 1) ? Whi : (g == 2) ? Who : Whc;
        row = ny * 64u + b4 * 16u + r;
    }
    // src read: 8 consecutive fp32 (32 B); a quad of lanes covers 128 B of one row
    const float* s = src + (size_t)row * 1024u + kt * 32u + kg * 8u;
    const float4 v0 = *(const float4*)s;
    const float4 v1 = *(const float4*)(s + 4);
    short8 pk;
    pk[0] = (short)f2bf(v0.x); pk[1] = (short)f2bf(v0.y);
    pk[2] = (short)f2bf(v0.z); pk[3] = (short)f2bf(v0.w);
    pk[4] = (short)f2bf(v1.x); pk[5] = (short)f2bf(v1.y);
    pk[6] = (short)f2bf(v1.z); pk[7] = (short)f2bf(v1.w);
    // dst write: wave-contiguous 1 KB
    *(short8*)(ws + (size_t)W * 512u + (uint32_t)l * 8u) = pk;
}

// ---------------------------------------------------------------------------
// Kernel 2: fused 4-gate GEMM + LSTM pointwise, 3-stage pipeline, 512 threads.
// Identical to round 6 except staging sources are packed chunks (contiguous DMA).
// Block: 512 threads (8 waves). Tile: 128 batch-rows x 64 hidden-cols x 4 gates.
// ONE s_barrier + one s_waitcnt vmcnt(3) per iteration; 3 chunks/wave/iter.
__global__ __launch_bounds__(512, 4)
void lstm_fused_kernel(const unsigned short* __restrict__ ws,
                       const float* __restrict__ c,
                       const float* __restrict__ bxf, const float* __restrict__ bhf,
                       const float* __restrict__ bxi, const float* __restrict__ bhi,
                       const float* __restrict__ bxo, const float* __restrict__ bho,
                       const float* __restrict__ bxc, const float* __restrict__ bhc,
                       float* __restrict__ out)
{
    __shared__ __align__(16) char lds[3 * LDS_BUF];

    const int tid  = threadIdx.x;
    const int w    = tid >> 6;     // 0..7
    const int lane = tid & 63;

    // XCD-aware block swizzle (1D grid of 512)
    const int bid = blockIdx.x;
    const int mx  = bid >> 4;                              // [0,32)
    const int ny  = ((bid & 7) << 1) | ((bid >> 3) & 1);   // [0,16)
    const int bm0 = mx * 128;
    const int bn0 = ny * 64;

    // staging: 24 packed chunks of 1 KB; wave w issues ch = w*3+i.
    // ch<8: A chunk ch; ch>=8: b=ch-8 -> gate g=b>>2, n-subtile b4=b&3.
    // srcP0/P1 = phase-0/1 chunk base (+lane*16B); kstr = element stride per kt.
    const unsigned short* srcP0[3];
    const unsigned short* srcP1[3];
    uint32_t kstr[3];
    uint32_t loff[3];   // wave-uniform LDS byte base (within a stage)
#pragma unroll
    for (int i = 0; i < 3; ++i) {
        const int ch = w * 3 + i;
        if (ch < 8) {
            // x chunk (mx, kt, ch): ((mx*32+kt)*8+ch)*512
            const uint32_t base = ((uint32_t)mx * 32u * 8u + (uint32_t)ch) * 512u;
            srcP0[i] = ws + base + (uint32_t)lane * 8u;
            srcP1[i] = srcP0[i] + (8u << 20);            // h at +8M... (x:0, h:8192 chunks*512=4M elems)
            kstr[i]  = 8u * 512u;                        // kt stride = 8 chunks
            loff[i]  = (uint32_t)ch * 1024u;
        } else {
            const int b  = ch - 8;
            const uint32_t g  = (uint32_t)b >> 2;
            const uint32_t b4 = (uint32_t)b & 3u;
            // Wx chunk: 16384*512 + (((ny*16)+(g*4)+b4)*32 + kt)*512
            const uint32_t base = (16384u + ((uint32_t)ny * 16u + g * 4u + b4) * 32u) * 512u;
            srcP0[i] = ws + base + (uint32_t)lane * 8u;
            srcP1[i] = srcP0[i] + (8192u * 512u);        // Wh chunks start 8192 later
            kstr[i]  = 512u;
            loff[i]  = 8192u + (uint32_t)b * 1024u;
        }
    }
    // fix h offset: h chunks start at chunk 8192 -> +8192*512 = +4M elems
    // (srcP1 for A was set with (8u<<20)=8M elems above; correct it)
#pragma unroll
    for (int i = 0; i < 3; ++i) {
        const int ch = w * 3 + i;
        if (ch < 8) srcP1[i] = srcP0[i] + 8192u * 512u;
    }

    const int wrow  = (w & 1) * 64;    // 4 m-tiles
    const int wcol  = (w >> 1) * 16;   // one 16-col group within each gate
    const int lrc   = lane & 15;       // frag row (A) / col (B)
    const int lquad = lane >> 4;       // frag k-group (x8 elements)

    // reader-side swizzle (pack wrote the same image): slot = lquad^((r>>1)&3)
    const uint32_t kslot = (((uint32_t)lquad ^ (((uint32_t)lrc >> 1) & 3u))) * 8u;

    uint32_t aoff[4];
#pragma unroll
    for (int mt = 0; mt < 4; ++mt)
        aoff[mt] = (uint32_t)((wrow + mt * 16 + lrc) * 32) + kslot;
    uint32_t boff[4];
#pragma unroll
    for (int g = 0; g < 4; ++g)
        boff[g] = (uint32_t)(g * 2048 + (wcol + lrc) * 32) + kslot;

    floatx4 acc[4][4];   // [gate][m-tile] = 64 fp32/lane
#pragma unroll
    for (int g = 0; g < 4; ++g)
#pragma unroll
        for (int mt = 0; mt < 4; ++mt)
            acc[g][mt] = (floatx4){0.f, 0.f, 0.f, 0.f};

    auto issue_loads = [&](int kt, uint32_t stage) {
        const int phase = kt >> 5;
        const uint32_t kk = (uint32_t)(kt & 31);
        const uint32_t bb = stage * LDS_BUF;
#pragma unroll
        for (int i = 0; i < 3; ++i) {
            const unsigned short* src = (phase ? srcP1[i] : srcP0[i]) + kk * kstr[i];
            __builtin_amdgcn_global_load_lds(AS1(src), AS3(lds + bb + loff[i]), 16, 0, 0);
        }
    };
    auto compute = [&](uint32_t stage) {
        const char* base = lds + stage * LDS_BUF;
        const bf16* lA = (const bf16*)base;
        const bf16* lB = (const bf16*)(base + 8192);
        short8 afr[4];
#pragma unroll
        for (int mt = 0; mt < 4; ++mt)
            afr[mt] = *(const short8*)(lA + aoff[mt]);
#pragma unroll
        for (int g = 0; g < 4; ++g) {
            const short8 bfr = *(const short8*)(lB + boff[g]);
#pragma unroll
            for (int mt = 0; mt < 4; ++mt)
                acc[g][mt] = __builtin_amdgcn_mfma_f32_16x16x32_bf16(
                    afr[mt], bfr, acc[g][mt], 0, 0, 0);
        }
    };

    // prologue: stages 0,1 in flight (6 outstanding/wave)
    issue_loads(0, 0);
    issue_loads(1, 1);

    uint32_t s_comp = 0;   // kt % 3
    uint32_t s_load = 2;   // (kt+2) % 3
    for (int kt = 0; kt < 62; ++kt) {
        // own loads(kt) retired; loads(kt+1) (3) stay in flight
        asm volatile("s_waitcnt vmcnt(3)\ns_barrier" ::: "memory");
        issue_loads(kt + 2, s_load);
        compute(s_comp);
        s_comp = (s_comp == 2) ? 0 : s_comp + 1;
        s_load = (s_load == 2) ? 0 : s_load + 1;
    }
    asm volatile("s_waitcnt vmcnt(3)\ns_barrier" ::: "memory");   // loads(62) done
    compute(s_comp);
    s_comp = (s_comp == 2) ? 0 : s_comp + 1;
    asm volatile("s_waitcnt vmcnt(0)\ns_barrier" ::: "memory");   // loads(63) done
    compute(s_comp);

    // epilogue.  C/D layout: col = lane&15, row = (lane>>4)*4 + reg
    float* out_ct = out;
    float* out_ht = out + (size_t)M_DIM * H_DIM;
    {
        const int col = bn0 + wcol + lrc;
        const float bf_ = bxf[col] + bhf[col];
        const float bi_ = bxi[col] + bhi[col];
        const float bo_ = bxo[col] + bho[col];
        const float bc_ = bxc[col] + bhc[col];
#pragma unroll
        for (int mt = 0; mt < 4; ++mt) {
#pragma unroll
            for (int r = 0; r < 4; ++r) {
                const int row = bm0 + wrow + mt * 16 + lquad * 4 + r;
                const float gf = acc[0][mt][r] + bf_;
                const float gi = acc[1][mt][r] + bi_;
                const float go = acc[2][mt][r] + bo_;
                const float gc = acc[3][mt][r] + bc_;
                const float f    = fast_sigmoid(gf);
                const float ii   = fast_sigmoid(gi);
                const float o    = fast_sigmoid(go);
                const float ctil = fast_tanh(gc);
                const float cv   = c[(size_t)row * H_DIM + col];
                const float ctn  = f * cv + ctil * ii;
                const float htn  = fast_tanh(ctn) * o;
                out_ct[(size_t)row * H_DIM + col] = ctn;
                out_ht[(size_t)row * H_DIM + col] = htn;
            }
        }
    }
}

extern "C" void kernel_launch(void* const* d_in, const int* in_sizes, int n_in,
                              void* d_out, int out_size, void* d_ws, size_t ws_size,
                              hipStream_t stream) {
    (void)in_sizes; (void)n_in; (void)out_size; (void)ws_size;
    const float* x   = (const float*)d_in[0];
    const float* c   = (const float*)d_in[1];
    const float* h   = (const float*)d_in[2];
    const float* Wxf = (const float*)d_in[3];  const float* bxf = (const float*)d_in[4];
    const float* Whf = (const float*)d_in[5];  const float* bhf = (const float*)d_in[6];
    const float* Wxi = (const float*)d_in[7];  const float* bxi = (const float*)d_in[8];
    const float* Whi = (const float*)d_in[9];  const float* bhi = (const float*)d_in[10];
    const float* Wxo = (const float*)d_in[11]; const float* bxo = (const float*)d_in[12];
    const float* Who = (const float*)d_in[13]; const float* bho = (const float*)d_in[14];
    const float* Wxc = (const float*)d_in[15]; const float* bxc = (const float*)d_in[16];
    const float* Whc = (const float*)d_in[17]; const float* bhc = (const float*)d_in[18];
    float* out = (float*)d_out;
    unsigned short* ws = (unsigned short*)d_ws;   // 32768 chunks x 1 KB = 32 MB

    pack_bf16<<<8192, 256, 0, stream>>>(x, h,
        Wxf, Wxi, Wxo, Wxc, Whf, Whi, Who, Whc, ws);

    lstm_fused_kernel<<<512, 512, 0, stream>>>(ws, c,
        bxf, bhf, bxi, bhi, bxo, bho, bxc, bhc, out);
}